// Round 3
// baseline (434.784 us; speedup 1.0000x reference)
//
#include <hip/hip_runtime.h>
#include <stdint.h>

#define LATENT 10
#define MAXLEN 80
#define STEPS  10
#define HIDDEN 32
#define BATCH  512

// ---------------------------------------------------------------------------
// Threefry-2x32, 20 rounds — bit-exact replica of jax threefry2x32_p.
// ---------------------------------------------------------------------------
__device__ __forceinline__ void tf2x32(uint32_t k0, uint32_t k1,
                                       uint32_t x0, uint32_t x1,
                                       uint32_t& o0, uint32_t& o1) {
  uint32_t ks2 = k0 ^ k1 ^ 0x1BD11BDAu;
  uint32_t v0 = x0 + k0;
  uint32_t v1 = x1 + k1;
#define TF_R(rot) { v0 += v1; v1 = (v1 << (rot)) | (v1 >> (32 - (rot))); v1 ^= v0; }
  TF_R(13) TF_R(15) TF_R(26) TF_R(6)
  v0 += k1;  v1 += ks2 + 1u;
  TF_R(17) TF_R(29) TF_R(16) TF_R(24)
  v0 += ks2; v1 += k0 + 2u;
  TF_R(13) TF_R(15) TF_R(26) TF_R(6)
  v0 += k0;  v1 += k1 + 3u;
  TF_R(17) TF_R(29) TF_R(16) TF_R(24)
  v0 += k1;  v1 += ks2 + 4u;
  TF_R(13) TF_R(15) TF_R(26) TF_R(6)
  v0 += ks2; v1 += k0 + 5u;
#undef TF_R
  o0 = v0; o1 = v1;
}

// JAX uniform(-0.99999994, 1) bits -> sqrt(2)*erfinv(u)  (XLA Giles polynomial)
__device__ __forceinline__ float bits_to_normal(uint32_t bits) {
  const float lo = -0.99999994f;                                 // nextafter(-1, 0)
  float f = __uint_as_float((bits >> 9) | 0x3f800000u) - 1.0f;   // [0,1)
  float u = fmaf(f, 2.0f, lo);                                   // (hi-lo) rounds to 2.0f
  u = fmaxf(u, lo);
  float w = -log1pf(-u * u);
  float p;
  if (w < 5.0f) {
    w -= 2.5f;
    p = 2.81022636e-08f;
    p = fmaf(p, w, 3.43273939e-07f);
    p = fmaf(p, w, -3.5233877e-06f);
    p = fmaf(p, w, -4.39150654e-06f);
    p = fmaf(p, w, 0.00021858087f);
    p = fmaf(p, w, -0.00125372503f);
    p = fmaf(p, w, -0.00417768164f);
    p = fmaf(p, w, 0.246640727f);
    p = fmaf(p, w, 1.50140941f);
  } else {
    w = sqrtf(w) - 3.0f;
    p = -0.000200214257f;
    p = fmaf(p, w, 0.000100950558f);
    p = fmaf(p, w, 0.00134934322f);
    p = fmaf(p, w, -0.00367342844f);
    p = fmaf(p, w, 0.00573950773f);
    p = fmaf(p, w, -0.0076224613f);
    p = fmaf(p, w, 0.00943887047f);
    p = fmaf(p, w, 1.00167406f);
    p = fmaf(p, w, 2.83297682f);
  }
  return 1.4142135623730951f * (p * u);
}

// ---------------------------------------------------------------------------
// One 32-lane half-wave per (i,b) chain. lane = j (hidden unit).
// 8 chains per 256-thread block; i is block-uniform.
// ---------------------------------------------------------------------------
__global__ __launch_bounds__(256, 4) void k_chain(
    const float* __restrict__ zmean, const float* __restrict__ zlv,
    const float* __restrict__ W1, const float* __restrict__ b1v,
    const float* __restrict__ W2, const float* __restrict__ b2v,
    float* __restrict__ outSeq, float* __restrict__ outErr) {
  const int tid = threadIdx.x;
  const int j = tid & 31;                     // hidden unit / lane-in-chain
  const int g = blockIdx.x * 8 + (tid >> 5);  // global chain id
  const int i = g >> 9;                       // 512 chains per i -> block-uniform
  const int b = g & 511;
  const int half = tid & 32;                  // half-wave base for shfl sources

  // ---- PRNG prologue: 110 normals per chain, 4 per lane (partitionable) ----
  // item idx = j + 32r -> (k = idx/10, d = idx%10); normal for draw k, dim d.
  float n4[4];
#pragma unroll
  for (int r = 0; r < 4; ++r) {
    int idx = j + 32 * r;
    float v = 0.0f;
    if (idx < (STEPS + 1) * LATENT) {
      int k = (idx * 205) >> 11;              // idx/10 for idx<128
      int d = idx - k * 10;
      uint32_t a, c, o0, o1;
      tf2x32(0u, 1337u, 0u, (uint32_t)(i * (STEPS + 1) + k), a, c);
      tf2x32(a, c, 0u, (uint32_t)(b * LATENT + d), o0, o1);
      v = bits_to_normal(o0 ^ o1);
    }
    n4[r] = v;
  }

  // ---- weights for this lane ----
  float w1x[LATENT];
#pragma unroll
  for (int d = 0; d < LATENT; ++d) w1x[d] = W1[(i * LATENT + d) * HIDDEN + j];
  const float wT = W1[(MAXLEN * LATENT) * HIDDEN + j];
  const float b1j = b1v[j];
  float w2[LATENT], b2[LATENT];
#pragma unroll
  for (int d = 0; d < LATENT; ++d) w2[d] = W2[j * LATENT + d];
#pragma unroll
  for (int d = 0; d < LATENT; ++d) b2[d] = b2v[d];

  // ---- prefix_j = sum_{l<i} mu[b,l,:] . W1[l*10:l*10+10, j] ----
  float pf0 = 0.0f, pf1 = 0.0f;
  for (int l = 0; l < i; ++l) {
    const float2* mrow = (const float2*)(zmean + (b * MAXLEN + l) * LATENT);
    float2 m0 = mrow[0], m1 = mrow[1], m2 = mrow[2], m3 = mrow[3], m4 = mrow[4];
    const float* wl = W1 + (l * LATENT) * HIDDEN + j;
    pf0 = fmaf(m0.x, wl[0 * HIDDEN], pf0);
    pf1 = fmaf(m0.y, wl[1 * HIDDEN], pf1);
    pf0 = fmaf(m1.x, wl[2 * HIDDEN], pf0);
    pf1 = fmaf(m1.y, wl[3 * HIDDEN], pf1);
    pf0 = fmaf(m2.x, wl[4 * HIDDEN], pf0);
    pf1 = fmaf(m2.y, wl[5 * HIDDEN], pf1);
    pf0 = fmaf(m3.x, wl[6 * HIDDEN], pf0);
    pf1 = fmaf(m3.y, wl[7 * HIDDEN], pf1);
    pf0 = fmaf(m4.x, wl[8 * HIDDEN], pf0);
    pf1 = fmaf(m4.y, wl[9 * HIDDEN], pf1);
  }
  const float prefj = pf0 + pf1;

  // ---- per-chain state (replicated across the 32 lanes) ----
  const int base = (b * MAXLEN + i) * LATENT;
  float mu[LATENT], sstd[LATENT], invs[LATENT], xt[LATENT], errs[LATENT];
#pragma unroll
  for (int d = 0; d < LATENT; ++d) {
    mu[d] = zmean[base + d];
    sstd[d] = sqrtf(expf(zlv[base + d]));
    invs[d] = 1.0f / sstd[d];
  }
#pragma unroll
  for (int d = 0; d < LATENT; ++d) {
    float n0 = __shfl(n4[0], half | d);       // item idx = d (draw 0)
    xt[d] = mu[d] + sstd[d] * n0;
    errs[d] = 0.0f;
  }

  const float SQRT_DT = 0.31622776601683794f; // sqrtf(0.1f)

#pragma unroll
  for (int s = 0; s < STEPS; ++s) {
    const float t = (float)i + (float)s * 0.1f;
    // hidden unit j
    float hj = prefj;
#pragma unroll
    for (int d = 0; d < LATENT; ++d) hj = fmaf(xt[d], w1x[d], hj);
    hj = fmaf(t, wT, hj) + b1j;
    hj = fmaxf(hj, 0.0f);
    // score: butterfly-reduce h_j * W2[j, d] over the 32 lanes
    float p[LATENT];
#pragma unroll
    for (int d = 0; d < LATENT; ++d) p[d] = hj * w2[d];
#pragma unroll
    for (int m = 1; m < 32; m <<= 1) {
#pragma unroll
      for (int d = 0; d < LATENT; ++d) p[d] += __shfl_xor(p[d], m);
    }
    // update (replicated on all lanes)
#pragma unroll
    for (int d = 0; d < LATENT; ++d) {
      const int idx = (s + 1) * LATENT + d;
      float nd = __shfl(n4[idx >> 5], half | (idx & 31));
      float sc = p[d] + b2[d];
      float logdx = (mu[d] - xt[d]) * invs[d];
      errs[d] += fabsf(logdx - sc);
      float inner = fmaf(0.5f * sstd[d], sc, nd * SQRT_DT);
      xt[d] = fmaf(sstd[d], inner, xt[d]);
    }
  }

  // ---- epilogue: lane d (<10) stores component d ----
  float xs = xt[0], es = errs[0];
#pragma unroll
  for (int d = 1; d < LATENT; ++d) {
    xs = (j == d) ? xt[d] : xs;
    es = (j == d) ? errs[d] : es;
  }
  if (j < LATENT) {
    outSeq[base + j] = xs;
    outErr[base + j] = es;
  }
}

// ---------------------------------------------------------------------------
extern "C" void kernel_launch(void* const* d_in, const int* in_sizes, int n_in,
                              void* d_out, int out_size, void* d_ws, size_t ws_size,
                              hipStream_t stream) {
  (void)in_sizes; (void)n_in; (void)d_ws; (void)ws_size; (void)out_size;
  const float* zmean = (const float*)d_in[0];
  const float* zlv   = (const float*)d_in[1];
  const float* W1    = (const float*)d_in[2];
  const float* b1v   = (const float*)d_in[3];
  const float* W2    = (const float*)d_in[4];
  const float* b2v   = (const float*)d_in[5];
  float* outSeq = (float*)d_out;
  float* outErr = outSeq + (size_t)BATCH * MAXLEN * LATENT;

  hipLaunchKernelGGL(k_chain, dim3(MAXLEN * BATCH / 8), dim3(256), 0, stream,
                     zmean, zlv, W1, b1v, W2, b2v, outSeq, outErr);
}

// Round 4
// 151.334 us; speedup vs baseline: 2.8730x; 2.8730x over previous
//
#include <hip/hip_runtime.h>
#include <stdint.h>

#define LATENT 10
#define MAXLEN 80
#define STEPS  10
#define HIDDEN 32
#define BATCH  512

// ---------------------------------------------------------------------------
// Threefry-2x32, 20 rounds — bit-exact replica of jax threefry2x32_p.
// ---------------------------------------------------------------------------
__device__ __forceinline__ void tf2x32(uint32_t k0, uint32_t k1,
                                       uint32_t x0, uint32_t x1,
                                       uint32_t& o0, uint32_t& o1) {
  uint32_t ks2 = k0 ^ k1 ^ 0x1BD11BDAu;
  uint32_t v0 = x0 + k0;
  uint32_t v1 = x1 + k1;
#define TF_R(rot) { v0 += v1; v1 = (v1 << (rot)) | (v1 >> (32 - (rot))); v1 ^= v0; }
  TF_R(13) TF_R(15) TF_R(26) TF_R(6)
  v0 += k1;  v1 += ks2 + 1u;
  TF_R(17) TF_R(29) TF_R(16) TF_R(24)
  v0 += ks2; v1 += k0 + 2u;
  TF_R(13) TF_R(15) TF_R(26) TF_R(6)
  v0 += k0;  v1 += k1 + 3u;
  TF_R(17) TF_R(29) TF_R(16) TF_R(24)
  v0 += k1;  v1 += ks2 + 4u;
  TF_R(13) TF_R(15) TF_R(26) TF_R(6)
  v0 += ks2; v1 += k0 + 5u;
#undef TF_R
  o0 = v0; o1 = v1;
}

// JAX uniform(-0.99999994, 1) bits -> sqrt(2)*erfinv(u)  (XLA Giles polynomial)
__device__ __forceinline__ float bits_to_normal(uint32_t bits) {
  const float lo = -0.99999994f;                                 // nextafter(-1, 0)
  float f = __uint_as_float((bits >> 9) | 0x3f800000u) - 1.0f;   // [0,1)
  float u = fmaf(f, 2.0f, lo);                                   // (hi-lo) rounds to 2.0f
  u = fmaxf(u, lo);
  float w = -log1pf(-u * u);
  float p;
  if (w < 5.0f) {
    w -= 2.5f;
    p = 2.81022636e-08f;
    p = fmaf(p, w, 3.43273939e-07f);
    p = fmaf(p, w, -3.5233877e-06f);
    p = fmaf(p, w, -4.39150654e-06f);
    p = fmaf(p, w, 0.00021858087f);
    p = fmaf(p, w, -0.00125372503f);
    p = fmaf(p, w, -0.00417768164f);
    p = fmaf(p, w, 0.246640727f);
    p = fmaf(p, w, 1.50140941f);
  } else {
    w = sqrtf(w) - 3.0f;
    p = -0.000200214257f;
    p = fmaf(p, w, 0.000100950558f);
    p = fmaf(p, w, 0.00134934322f);
    p = fmaf(p, w, -0.00367342844f);
    p = fmaf(p, w, 0.00573950773f);
    p = fmaf(p, w, -0.0076224613f);
    p = fmaf(p, w, 0.00943887047f);
    p = fmaf(p, w, 1.00167406f);
    p = fmaf(p, w, 2.83297682f);
  }
  return 1.4142135623730951f * (p * u);
}

// ---------------------------------------------------------------------------
// Phase 1: pref[i][b][j] = sum_{l<i} mu[b,l,:] . W1[l*10 : l*10+10, j]
// one thread per (b,j); writes coalesced (j fastest).
// ---------------------------------------------------------------------------
__global__ __launch_bounds__(256) void k_prefix(
    const float* __restrict__ zmean, const float* __restrict__ W1,
    float* __restrict__ pref) {
  int tid = blockIdx.x * 256 + threadIdx.x;   // 0..16383
  int j = tid & 31, b = tid >> 5;
  pref[(0 * BATCH + b) * HIDDEN + j] = 0.0f;
  float pf0 = 0.0f, pf1 = 0.0f;
  for (int l = 0; l < MAXLEN - 1; ++l) {
    const float2* mrow = (const float2*)(zmean + (b * MAXLEN + l) * LATENT);
    float2 m0 = mrow[0], m1 = mrow[1], m2 = mrow[2], m3 = mrow[3], m4 = mrow[4];
    const float* wl = W1 + (l * LATENT) * HIDDEN + j;
    pf0 = fmaf(m0.x, wl[0 * HIDDEN], pf0);
    pf1 = fmaf(m0.y, wl[1 * HIDDEN], pf1);
    pf0 = fmaf(m1.x, wl[2 * HIDDEN], pf0);
    pf1 = fmaf(m1.y, wl[3 * HIDDEN], pf1);
    pf0 = fmaf(m2.x, wl[4 * HIDDEN], pf0);
    pf1 = fmaf(m2.y, wl[5 * HIDDEN], pf1);
    pf0 = fmaf(m3.x, wl[6 * HIDDEN], pf0);
    pf1 = fmaf(m3.y, wl[7 * HIDDEN], pf1);
    pf0 = fmaf(m4.x, wl[8 * HIDDEN], pf0);
    pf1 = fmaf(m4.y, wl[9 * HIDDEN], pf1);
    pref[((l + 1) * BATCH + b) * HIDDEN + j] = pf0 + pf1;
  }
}

// ---------------------------------------------------------------------------
// Phase 2: all 4.5M normals. nrm[ik][d][b], ik = i*11+k block-uniform.
// partitionable threefry: subkey = tf(key, (0, ik)); bits = o0^o1 of
// tf(subkey, (0, b*10+d)).
// ---------------------------------------------------------------------------
__global__ __launch_bounds__(256) void k_normals(float* __restrict__ nrm) {
  int blk = blockIdx.x;                 // 0..17599
  int ik  = blk / 20;                   // block-uniform -> scalar threefry
  int e   = (blk % 20) * 256 + threadIdx.x;  // 0..5119 = d*512 + b
  int d = e >> 9, b = e & 511;
  uint32_t a, c, o0, o1;
  tf2x32(0u, 1337u, 0u, (uint32_t)ik, a, c);
  tf2x32(a, c, 0u, (uint32_t)(b * LATENT + d), o0, o1);
  nrm[ik * 5120 + e] = bits_to_normal(o0 ^ o1);
}

// ---------------------------------------------------------------------------
// Phase 3: one thread per (i,b) chain; prefix and normals come from ws.
// ---------------------------------------------------------------------------
__global__ __launch_bounds__(64) void k_chain(
    const float* __restrict__ zmean, const float* __restrict__ zlv,
    const float* __restrict__ W1, const float* __restrict__ b1v,
    const float* __restrict__ W2, const float* __restrict__ b2v,
    const float* __restrict__ pref, const float* __restrict__ nrm,
    float* __restrict__ outSeq, float* __restrict__ outErr) {
  const int i = blockIdx.x >> 3;                       // wave-uniform
  const int b = ((blockIdx.x & 7) << 6) + threadIdx.x; // 0..511

  // fold b1 and i*rowT into the per-thread hidden base
  const float* rowT = W1 + (MAXLEN * LATENT) * HIDDEN;
  float pf[HIDDEN], wT[HIDDEN];
  {
    const float4* pp = (const float4*)(pref + ((size_t)i * BATCH + b) * HIDDEN);
    const float fi = (float)i;
#pragma unroll
    for (int q = 0; q < 8; ++q) {
      float4 v = pp[q];
      pf[4 * q + 0] = v.x; pf[4 * q + 1] = v.y;
      pf[4 * q + 2] = v.z; pf[4 * q + 3] = v.w;
    }
#pragma unroll
    for (int j = 0; j < HIDDEN; ++j) {
      wT[j] = rowT[j];
      pf[j] = fmaf(fi, wT[j], pf[j] + b1v[j]);
    }
  }

  const int base = (b * MAXLEN + i) * LATENT;
  float mu[LATENT], sstd[LATENT], invs[LATENT], xt[LATENT], errs[LATENT];
#pragma unroll
  for (int d = 0; d < LATENT; ++d) {
    mu[d] = zmean[base + d];
    sstd[d] = sqrtf(expf(zlv[base + d]));
    invs[d] = 1.0f / sstd[d];
  }
  const float* nbase = nrm + (size_t)i * ((STEPS + 1) * BATCH * LATENT) + b;
#pragma unroll
  for (int d = 0; d < LATENT; ++d) {
    float n0 = nbase[d * BATCH];                       // k = 0
    xt[d] = mu[d] + sstd[d] * n0;
    errs[d] = 0.0f;
  }

  const float* W1i = W1 + (i * LATENT) * HIDDEN;
  const float SQRT_DT = 0.31622776601683794f;

  for (int s = 0; s < STEPS; ++s) {
    // prefetch this step's noise (k = s+1), coalesced across b
    float nd[LATENT];
#pragma unroll
    for (int d = 0; d < LATENT; ++d)
      nd[d] = nbase[(s + 1) * (BATCH * LATENT) + d * BATCH];

    const float ts = (float)s * 0.1f;
    float h[HIDDEN];
#pragma unroll
    for (int j = 0; j < HIDDEN; ++j) h[j] = fmaf(ts, wT[j], pf[j]);
#pragma unroll
    for (int d = 0; d < LATENT; ++d) {
      const float xd = xt[d];
      const float4* w4 = (const float4*)(W1i + d * HIDDEN);
#pragma unroll
      for (int q = 0; q < 8; ++q) {
        float4 w = w4[q];
        h[4 * q + 0] = fmaf(xd, w.x, h[4 * q + 0]);
        h[4 * q + 1] = fmaf(xd, w.y, h[4 * q + 1]);
        h[4 * q + 2] = fmaf(xd, w.z, h[4 * q + 2]);
        h[4 * q + 3] = fmaf(xd, w.w, h[4 * q + 3]);
      }
    }
    float sc[LATENT];
#pragma unroll
    for (int d = 0; d < LATENT; ++d) sc[d] = b2v[d];
#pragma unroll
    for (int j = 0; j < HIDDEN; ++j) {
      const float hj = fmaxf(h[j], 0.0f);
      const float2* w2r = (const float2*)(W2 + j * LATENT);  // j*10 even -> 8B aligned
#pragma unroll
      for (int q = 0; q < 5; ++q) {
        float2 w = w2r[q];
        sc[2 * q + 0] = fmaf(hj, w.x, sc[2 * q + 0]);
        sc[2 * q + 1] = fmaf(hj, w.y, sc[2 * q + 1]);
      }
    }
#pragma unroll
    for (int d = 0; d < LATENT; ++d) {
      float logdx = (mu[d] - xt[d]) * invs[d];
      errs[d] += fabsf(logdx - sc[d]);
      float inner = fmaf(0.5f * sstd[d], sc[d], nd[d] * SQRT_DT);
      xt[d] = fmaf(sstd[d], inner, xt[d]);
    }
  }
#pragma unroll
  for (int d = 0; d < LATENT; ++d) {
    outSeq[base + d] = xt[d];
    outErr[base + d] = errs[d];
  }
}

// ---------------------------------------------------------------------------
// Fallback (ws too small): round-2 mono kernel, known-correct.
// ---------------------------------------------------------------------------
__global__ __launch_bounds__(64) void k_mono(
    const float* __restrict__ zmean, const float* __restrict__ zlv,
    const float* __restrict__ W1, const float* __restrict__ b1v,
    const float* __restrict__ W2, const float* __restrict__ b2v,
    float* __restrict__ outSeq, float* __restrict__ outErr) {
  int i = blockIdx.x >> 3;
  int b = ((blockIdx.x & 7) << 6) + threadIdx.x;
  float pref[HIDDEN];
#pragma unroll
  for (int j = 0; j < HIDDEN; ++j) pref[j] = 0.0f;
  for (int l = 0; l < i; ++l) {
    const float* mrow = zmean + (b * MAXLEN + l) * LATENT;
    const float* wrow = W1 + (l * LATENT) * HIDDEN;
#pragma unroll
    for (int d = 0; d < LATENT; ++d) {
      float m = mrow[d];
#pragma unroll
      for (int j = 0; j < HIDDEN; ++j) pref[j] = fmaf(m, wrow[d * HIDDEN + j], pref[j]);
    }
  }
  const int base = (b * MAXLEN + i) * LATENT;
  float mu[LATENT], sstd[LATENT], xt[LATENT], errs[LATENT];
#pragma unroll
  for (int d = 0; d < LATENT; ++d) {
    mu[d] = zmean[base + d];
    sstd[d] = sqrtf(expf(zlv[base + d]));
  }
  float n0[LATENT];
  {
    uint32_t a, c;
    tf2x32(0u, 1337u, 0u, (uint32_t)(i * (STEPS + 1)), a, c);
#pragma unroll
    for (int d = 0; d < LATENT; ++d) {
      uint32_t o0, o1;
      tf2x32(a, c, 0u, (uint32_t)(b * LATENT + d), o0, o1);
      n0[d] = bits_to_normal(o0 ^ o1);
    }
  }
#pragma unroll
  for (int d = 0; d < LATENT; ++d) { xt[d] = mu[d] + sstd[d] * n0[d]; errs[d] = 0.0f; }
  const float* rowT  = W1 + (MAXLEN * LATENT) * HIDDEN;
  const float* rowsI = W1 + (i * LATENT) * HIDDEN;
  const float SQRT_DT = 0.31622776601683794f;
  for (int s = 0; s < STEPS; ++s) {
    float t = (float)i + (float)s * 0.1f;
    float h[HIDDEN];
#pragma unroll
    for (int j = 0; j < HIDDEN; ++j) h[j] = pref[j];
#pragma unroll
    for (int d = 0; d < LATENT; ++d) {
      float xd = xt[d];
      const float* row = rowsI + d * HIDDEN;
#pragma unroll
      for (int j = 0; j < HIDDEN; ++j) h[j] = fmaf(xd, row[j], h[j]);
    }
    float sc[LATENT];
#pragma unroll
    for (int d = 0; d < LATENT; ++d) sc[d] = b2v[d];
#pragma unroll
    for (int j = 0; j < HIDDEN; ++j) {
      float hj = fmaf(t, rowT[j], h[j]) + b1v[j];
      hj = fmaxf(hj, 0.0f);
      const float* w2r = W2 + j * LATENT;
#pragma unroll
      for (int d = 0; d < LATENT; ++d) sc[d] = fmaf(hj, w2r[d], sc[d]);
    }
    float nd[LATENT];
    {
      uint32_t a, c;
      tf2x32(0u, 1337u, 0u, (uint32_t)(i * (STEPS + 1) + s + 1), a, c);
#pragma unroll
      for (int d = 0; d < LATENT; ++d) {
        uint32_t o0, o1;
        tf2x32(a, c, 0u, (uint32_t)(b * LATENT + d), o0, o1);
        nd[d] = bits_to_normal(o0 ^ o1);
      }
    }
#pragma unroll
    for (int d = 0; d < LATENT; ++d) {
      float logdx = -(xt[d] - mu[d]) / sstd[d];
      errs[d] += fabsf(logdx - sc[d]);
      float dW = nd[d] * SQRT_DT;
      xt[d] = xt[d] + (0.5f * (sstd[d] * sstd[d])) * sc[d] + sstd[d] * dW;
    }
  }
#pragma unroll
  for (int d = 0; d < LATENT; ++d) {
    outSeq[base + d] = xt[d];
    outErr[base + d] = errs[d];
  }
}

// ---------------------------------------------------------------------------
extern "C" void kernel_launch(void* const* d_in, const int* in_sizes, int n_in,
                              void* d_out, int out_size, void* d_ws, size_t ws_size,
                              hipStream_t stream) {
  (void)in_sizes; (void)n_in; (void)out_size;
  const float* zmean = (const float*)d_in[0];
  const float* zlv   = (const float*)d_in[1];
  const float* W1    = (const float*)d_in[2];
  const float* b1v   = (const float*)d_in[3];
  const float* W2    = (const float*)d_in[4];
  const float* b2v   = (const float*)d_in[5];
  float* outSeq = (float*)d_out;
  float* outErr = outSeq + (size_t)BATCH * MAXLEN * LATENT;

  const size_t prefBytes = (size_t)MAXLEN * BATCH * HIDDEN * sizeof(float);                 // 5,242,880
  const size_t nrmBytes  = (size_t)MAXLEN * (STEPS + 1) * BATCH * LATENT * sizeof(float);   // 18,022,400

  if (ws_size >= prefBytes + nrmBytes) {
    float* pref = (float*)d_ws;
    float* nrm  = (float*)((char*)d_ws + prefBytes);
    hipLaunchKernelGGL(k_prefix, dim3(64), dim3(256), 0, stream, zmean, W1, pref);
    hipLaunchKernelGGL(k_normals, dim3(MAXLEN * (STEPS + 1) * 20), dim3(256), 0, stream, nrm);
    hipLaunchKernelGGL(k_chain, dim3(MAXLEN * 8), dim3(64), 0, stream,
                       zmean, zlv, W1, b1v, W2, b2v, pref, nrm, outSeq, outErr);
  } else {
    hipLaunchKernelGGL(k_mono, dim3(MAXLEN * 8), dim3(64), 0, stream,
                       zmean, zlv, W1, b1v, W2, b2v, outSeq, outErr);
  }
}

// Round 5
// 132.448 us; speedup vs baseline: 3.2827x; 1.1426x over previous
//
#include <hip/hip_runtime.h>
#include <stdint.h>

#define LATENT 10
#define MAXLEN 80
#define STEPS  10
#define HIDDEN 32
#define BATCH  512
#define NSEG   4
#define SEGL   20   // MAXLEN / NSEG

// ---------------------------------------------------------------------------
// Threefry-2x32, 20 rounds — bit-exact replica of jax threefry2x32_p.
// ---------------------------------------------------------------------------
__device__ __forceinline__ void tf2x32(uint32_t k0, uint32_t k1,
                                       uint32_t x0, uint32_t x1,
                                       uint32_t& o0, uint32_t& o1) {
  uint32_t ks2 = k0 ^ k1 ^ 0x1BD11BDAu;
  uint32_t v0 = x0 + k0;
  uint32_t v1 = x1 + k1;
#define TF_R(rot) { v0 += v1; v1 = (v1 << (rot)) | (v1 >> (32 - (rot))); v1 ^= v0; }
  TF_R(13) TF_R(15) TF_R(26) TF_R(6)
  v0 += k1;  v1 += ks2 + 1u;
  TF_R(17) TF_R(29) TF_R(16) TF_R(24)
  v0 += ks2; v1 += k0 + 2u;
  TF_R(13) TF_R(15) TF_R(26) TF_R(6)
  v0 += k0;  v1 += k1 + 3u;
  TF_R(17) TF_R(29) TF_R(16) TF_R(24)
  v0 += k1;  v1 += ks2 + 4u;
  TF_R(13) TF_R(15) TF_R(26) TF_R(6)
  v0 += ks2; v1 += k0 + 5u;
#undef TF_R
  o0 = v0; o1 = v1;
}

// JAX uniform(-0.99999994, 1) bits -> sqrt(2)*erfinv(u)  (XLA Giles polynomial)
__device__ __forceinline__ float bits_to_normal(uint32_t bits) {
  const float lo = -0.99999994f;                                 // nextafter(-1, 0)
  float f = __uint_as_float((bits >> 9) | 0x3f800000u) - 1.0f;   // [0,1)
  float u = fmaf(f, 2.0f, lo);                                   // (hi-lo) rounds to 2.0f
  u = fmaxf(u, lo);
  float w = -log1pf(-u * u);
  float p;
  if (w < 5.0f) {
    w -= 2.5f;
    p = 2.81022636e-08f;
    p = fmaf(p, w, 3.43273939e-07f);
    p = fmaf(p, w, -3.5233877e-06f);
    p = fmaf(p, w, -4.39150654e-06f);
    p = fmaf(p, w, 0.00021858087f);
    p = fmaf(p, w, -0.00125372503f);
    p = fmaf(p, w, -0.00417768164f);
    p = fmaf(p, w, 0.246640727f);
    p = fmaf(p, w, 1.50140941f);
  } else {
    w = sqrtf(w) - 3.0f;
    p = -0.000200214257f;
    p = fmaf(p, w, 0.000100950558f);
    p = fmaf(p, w, 0.00134934322f);
    p = fmaf(p, w, -0.00367342844f);
    p = fmaf(p, w, 0.00573950773f);
    p = fmaf(p, w, -0.0076224613f);
    p = fmaf(p, w, 0.00943887047f);
    p = fmaf(p, w, 1.00167406f);
    p = fmaf(p, w, 2.83297682f);
  }
  return 1.4142135623730951f * (p * u);
}

// ---------------------------------------------------------------------------
// Fused phase 1: blocks [0,256) do segmented prefix scans; blocks [256, 17856)
// compute the 4.5M normals. The two jobs are independent.
//
// prefix: local[i][b][j] = sum_{l in seg(i), l<i} mu[b,l,:].W1[l*10+d, j]
//         segtot[s][b][j] = full 20-l sum of segment s
// normals: nrm[ik][d][b] = N(0,1) draw, partitionable threefry
// ---------------------------------------------------------------------------
__global__ __launch_bounds__(256) void k_pre(
    const float* __restrict__ zmean, const float* __restrict__ W1,
    float* __restrict__ localp, float* __restrict__ segtot,
    float* __restrict__ nrm) {
  if (blockIdx.x < 256) {
    // ---- prefix segments: thread = (s, b, j) ----
    int id = blockIdx.x * 256 + threadIdx.x;   // 0..65535
    int s = id >> 14;                          // block-uniform
    int r = id & 16383;
    int b = r >> 5, j = r & 31;
    localp[((s * SEGL) * BATCH + b) * HIDDEN + j] = 0.0f;  // t = 0
    float pf0 = 0.0f, pf1 = 0.0f;
    for (int t = 1; t <= SEGL; ++t) {
      int l = s * SEGL + t - 1;
      const float2* mrow = (const float2*)(zmean + (b * MAXLEN + l) * LATENT);
      float2 m0 = mrow[0], m1 = mrow[1], m2 = mrow[2], m3 = mrow[3], m4 = mrow[4];
      const float* wl = W1 + (l * LATENT) * HIDDEN + j;
      pf0 = fmaf(m0.x, wl[0 * HIDDEN], pf0);
      pf1 = fmaf(m0.y, wl[1 * HIDDEN], pf1);
      pf0 = fmaf(m1.x, wl[2 * HIDDEN], pf0);
      pf1 = fmaf(m1.y, wl[3 * HIDDEN], pf1);
      pf0 = fmaf(m2.x, wl[4 * HIDDEN], pf0);
      pf1 = fmaf(m2.y, wl[5 * HIDDEN], pf1);
      pf0 = fmaf(m3.x, wl[6 * HIDDEN], pf0);
      pf1 = fmaf(m3.y, wl[7 * HIDDEN], pf1);
      pf0 = fmaf(m4.x, wl[8 * HIDDEN], pf0);
      pf1 = fmaf(m4.y, wl[9 * HIDDEN], pf1);
      if (t < SEGL)
        localp[((s * SEGL + t) * BATCH + b) * HIDDEN + j] = pf0 + pf1;
    }
    segtot[(s * BATCH + b) * HIDDEN + j] = pf0 + pf1;
  } else {
    // ---- normals: blk in [0, 17600) ----
    int blk = blockIdx.x - 256;
    int ik  = blk / 20;                        // block-uniform -> scalar threefry
    int e   = (blk % 20) * 256 + threadIdx.x;  // 0..5119 = d*512 + b
    int d = e >> 9, b = e & 511;
    uint32_t a, c, o0, o1;
    tf2x32(0u, 1337u, 0u, (uint32_t)ik, a, c);
    tf2x32(a, c, 0u, (uint32_t)(b * LATENT + d), o0, o1);
    nrm[ik * 5120 + e] = bits_to_normal(o0 ^ o1);
  }
}

// ---------------------------------------------------------------------------
// Phase 2: 4 lanes per (i,b) chain; lane q owns hidden units [8q, 8q+8).
// 64 chains per 256-thread block; i is block-uniform (8 blocks per i).
// ---------------------------------------------------------------------------
__global__ __launch_bounds__(256) void k_chain(
    const float* __restrict__ zmean, const float* __restrict__ zlv,
    const float* __restrict__ W1, const float* __restrict__ b1v,
    const float* __restrict__ W2, const float* __restrict__ b2v,
    const float* __restrict__ localp, const float* __restrict__ segtot,
    const float* __restrict__ nrm,
    float* __restrict__ outSeq, float* __restrict__ outErr) {
  const int tid = threadIdx.x;
  const int q = tid & 3;                       // lane-in-chain
  const int jb = q * 8;                        // first hidden unit of this lane
  const int i = blockIdx.x >> 3;               // block-uniform
  const int b = ((blockIdx.x & 7) << 6) + (tid >> 2);

  // ---- hidden-base: pf[j'] = local[i] + sum_{s'<i/20} segtot[s'] + b1 + i*wT
  const float* rowT = W1 + (MAXLEN * LATENT) * HIDDEN;
  float pf[8], wT[8];
  {
    const float4* lp = (const float4*)(localp + ((size_t)i * BATCH + b) * HIDDEN + jb);
    float4 l0 = lp[0], l1 = lp[1];
    pf[0] = l0.x; pf[1] = l0.y; pf[2] = l0.z; pf[3] = l0.w;
    pf[4] = l1.x; pf[5] = l1.y; pf[6] = l1.z; pf[7] = l1.w;
    const int shi = i / SEGL;                  // uniform
    for (int s = 0; s < shi; ++s) {
      const float4* st = (const float4*)(segtot + ((size_t)s * BATCH + b) * HIDDEN + jb);
      float4 t0 = st[0], t1 = st[1];
      pf[0] += t0.x; pf[1] += t0.y; pf[2] += t0.z; pf[3] += t0.w;
      pf[4] += t1.x; pf[5] += t1.y; pf[6] += t1.z; pf[7] += t1.w;
    }
    const float fi = (float)i;
#pragma unroll
    for (int k = 0; k < 8; ++k) {
      wT[k] = rowT[jb + k];
      pf[k] = fmaf(fi, wT[k], pf[k] + b1v[jb + k]);
    }
  }

  // ---- replicated per-chain latent state ----
  const int base = (b * MAXLEN + i) * LATENT;
  float mu[LATENT], sstd[LATENT], invs[LATENT], xt[LATENT], errs[LATENT], b2[LATENT];
  {
    const float2* zm = (const float2*)(zmean + base);
    const float2* zl = (const float2*)(zlv + base);
#pragma unroll
    for (int p = 0; p < 5; ++p) {
      float2 m = zm[p], v = zl[p];
      mu[2 * p] = m.x; mu[2 * p + 1] = m.y;
      sstd[2 * p] = sqrtf(expf(v.x));
      sstd[2 * p + 1] = sqrtf(expf(v.y));
    }
  }
#pragma unroll
  for (int d = 0; d < LATENT; ++d) {
    invs[d] = 1.0f / sstd[d];
    b2[d] = b2v[d];
    errs[d] = 0.0f;
  }
  const float* nbase = nrm + (size_t)i * ((STEPS + 1) * BATCH * LATENT) + b;
#pragma unroll
  for (int d = 0; d < LATENT; ++d)
    xt[d] = fmaf(sstd[d], nbase[d * BATCH], mu[d]);

  const float* W1i = W1 + (i * LATENT) * HIDDEN + jb;
  const float* W2q = W2 + jb * LATENT;
  const float SQRT_DT = 0.31622776601683794f;

  for (int s = 0; s < STEPS; ++s) {
    // prefetch this step's noise (k = s+1)
    float nd[LATENT];
    const float* np = nbase + (s + 1) * (BATCH * LATENT);
#pragma unroll
    for (int d = 0; d < LATENT; ++d) nd[d] = np[d * BATCH];

    const float ts = (float)s * 0.1f;
    float h[8];
#pragma unroll
    for (int k = 0; k < 8; ++k) h[k] = fmaf(ts, wT[k], pf[k]);
#pragma unroll
    for (int d = 0; d < LATENT; ++d) {
      const float xd = xt[d];
      const float4* w4 = (const float4*)(W1i + d * HIDDEN);
      float4 w0 = w4[0], w1 = w4[1];
      h[0] = fmaf(xd, w0.x, h[0]); h[1] = fmaf(xd, w0.y, h[1]);
      h[2] = fmaf(xd, w0.z, h[2]); h[3] = fmaf(xd, w0.w, h[3]);
      h[4] = fmaf(xd, w1.x, h[4]); h[5] = fmaf(xd, w1.y, h[5]);
      h[6] = fmaf(xd, w1.z, h[6]); h[7] = fmaf(xd, w1.w, h[7]);
    }
    // partial score over this lane's 8 hidden units
    float sc[LATENT];
#pragma unroll
    for (int d = 0; d < LATENT; ++d) sc[d] = 0.0f;
#pragma unroll
    for (int k = 0; k < 8; ++k) {
      const float hj = fmaxf(h[k], 0.0f);
      const float2* w2r = (const float2*)(W2q + k * LATENT);
#pragma unroll
      for (int p = 0; p < 5; ++p) {
        float2 w = w2r[p];
        sc[2 * p] = fmaf(hj, w.x, sc[2 * p]);
        sc[2 * p + 1] = fmaf(hj, w.y, sc[2 * p + 1]);
      }
    }
    // reduce across the 4 lanes of the chain
#pragma unroll
    for (int m = 1; m < 4; m <<= 1) {
#pragma unroll
      for (int d = 0; d < LATENT; ++d) sc[d] += __shfl_xor(sc[d], m);
    }
    // update (replicated on the 4 lanes)
#pragma unroll
    for (int d = 0; d < LATENT; ++d) {
      float st = sc[d] + b2[d];
      float logdx = (mu[d] - xt[d]) * invs[d];
      errs[d] += fabsf(logdx - st);
      float inner = fmaf(0.5f * sstd[d], st, nd[d] * SQRT_DT);
      xt[d] = fmaf(sstd[d], inner, xt[d]);
    }
  }

  // ---- epilogue: lane (d & 3) stores dim d ----
#pragma unroll
  for (int d = 0; d < LATENT; ++d) {
    if ((d & 3) == q) {
      outSeq[base + d] = xt[d];
      outErr[base + d] = errs[d];
    }
  }
}

// ---------------------------------------------------------------------------
// Fallback (ws too small): known-correct mono kernel.
// ---------------------------------------------------------------------------
__global__ __launch_bounds__(64) void k_mono(
    const float* __restrict__ zmean, const float* __restrict__ zlv,
    const float* __restrict__ W1, const float* __restrict__ b1v,
    const float* __restrict__ W2, const float* __restrict__ b2v,
    float* __restrict__ outSeq, float* __restrict__ outErr) {
  int i = blockIdx.x >> 3;
  int b = ((blockIdx.x & 7) << 6) + threadIdx.x;
  float pref[HIDDEN];
#pragma unroll
  for (int j = 0; j < HIDDEN; ++j) pref[j] = 0.0f;
  for (int l = 0; l < i; ++l) {
    const float* mrow = zmean + (b * MAXLEN + l) * LATENT;
    const float* wrow = W1 + (l * LATENT) * HIDDEN;
#pragma unroll
    for (int d = 0; d < LATENT; ++d) {
      float m = mrow[d];
#pragma unroll
      for (int j = 0; j < HIDDEN; ++j) pref[j] = fmaf(m, wrow[d * HIDDEN + j], pref[j]);
    }
  }
  const int base = (b * MAXLEN + i) * LATENT;
  float mu[LATENT], sstd[LATENT], xt[LATENT], errs[LATENT];
#pragma unroll
  for (int d = 0; d < LATENT; ++d) {
    mu[d] = zmean[base + d];
    sstd[d] = sqrtf(expf(zlv[base + d]));
  }
  float n0[LATENT];
  {
    uint32_t a, c;
    tf2x32(0u, 1337u, 0u, (uint32_t)(i * (STEPS + 1)), a, c);
#pragma unroll
    for (int d = 0; d < LATENT; ++d) {
      uint32_t o0, o1;
      tf2x32(a, c, 0u, (uint32_t)(b * LATENT + d), o0, o1);
      n0[d] = bits_to_normal(o0 ^ o1);
    }
  }
#pragma unroll
  for (int d = 0; d < LATENT; ++d) { xt[d] = mu[d] + sstd[d] * n0[d]; errs[d] = 0.0f; }
  const float* rowT  = W1 + (MAXLEN * LATENT) * HIDDEN;
  const float* rowsI = W1 + (i * LATENT) * HIDDEN;
  const float SQRT_DT = 0.31622776601683794f;
  for (int s = 0; s < STEPS; ++s) {
    float t = (float)i + (float)s * 0.1f;
    float h[HIDDEN];
#pragma unroll
    for (int j = 0; j < HIDDEN; ++j) h[j] = pref[j];
#pragma unroll
    for (int d = 0; d < LATENT; ++d) {
      float xd = xt[d];
      const float* row = rowsI + d * HIDDEN;
#pragma unroll
      for (int j = 0; j < HIDDEN; ++j) h[j] = fmaf(xd, row[j], h[j]);
    }
    float sc[LATENT];
#pragma unroll
    for (int d = 0; d < LATENT; ++d) sc[d] = b2v[d];
#pragma unroll
    for (int j = 0; j < HIDDEN; ++j) {
      float hj = fmaf(t, rowT[j], h[j]) + b1v[j];
      hj = fmaxf(hj, 0.0f);
      const float* w2r = W2 + j * LATENT;
#pragma unroll
      for (int d = 0; d < LATENT; ++d) sc[d] = fmaf(hj, w2r[d], sc[d]);
    }
    float nd[LATENT];
    {
      uint32_t a, c;
      tf2x32(0u, 1337u, 0u, (uint32_t)(i * (STEPS + 1) + s + 1), a, c);
#pragma unroll
      for (int d = 0; d < LATENT; ++d) {
        uint32_t o0, o1;
        tf2x32(a, c, 0u, (uint32_t)(b * LATENT + d), o0, o1);
        nd[d] = bits_to_normal(o0 ^ o1);
      }
    }
#pragma unroll
    for (int d = 0; d < LATENT; ++d) {
      float logdx = -(xt[d] - mu[d]) / sstd[d];
      errs[d] += fabsf(logdx - sc[d]);
      float dW = nd[d] * SQRT_DT;
      xt[d] = xt[d] + (0.5f * (sstd[d] * sstd[d])) * sc[d] + sstd[d] * dW;
    }
  }
#pragma unroll
  for (int d = 0; d < LATENT; ++d) {
    outSeq[base + d] = xt[d];
    outErr[base + d] = errs[d];
  }
}

// ---------------------------------------------------------------------------
extern "C" void kernel_launch(void* const* d_in, const int* in_sizes, int n_in,
                              void* d_out, int out_size, void* d_ws, size_t ws_size,
                              hipStream_t stream) {
  (void)in_sizes; (void)n_in; (void)out_size;
  const float* zmean = (const float*)d_in[0];
  const float* zlv   = (const float*)d_in[1];
  const float* W1    = (const float*)d_in[2];
  const float* b1v   = (const float*)d_in[3];
  const float* W2    = (const float*)d_in[4];
  const float* b2v   = (const float*)d_in[5];
  float* outSeq = (float*)d_out;
  float* outErr = outSeq + (size_t)BATCH * MAXLEN * LATENT;

  const size_t nrmBytes   = (size_t)MAXLEN * (STEPS + 1) * BATCH * LATENT * sizeof(float); // 18,022,400
  const size_t localBytes = (size_t)MAXLEN * BATCH * HIDDEN * sizeof(float);               // 5,242,880
  const size_t segBytes   = (size_t)NSEG * BATCH * HIDDEN * sizeof(float);                 // 262,144

  if (ws_size >= nrmBytes + localBytes + segBytes) {
    float* nrm    = (float*)d_ws;
    float* localp = (float*)((char*)d_ws + nrmBytes);
    float* segtot = (float*)((char*)d_ws + nrmBytes + localBytes);
    hipLaunchKernelGGL(k_pre, dim3(256 + MAXLEN * (STEPS + 1) * 20), dim3(256), 0, stream,
                       zmean, W1, localp, segtot, nrm);
    hipLaunchKernelGGL(k_chain, dim3(MAXLEN * 8), dim3(256), 0, stream,
                       zmean, zlv, W1, b1v, W2, b2v, localp, segtot, nrm, outSeq, outErr);
  } else {
    hipLaunchKernelGGL(k_mono, dim3(MAXLEN * 8), dim3(64), 0, stream,
                       zmean, zlv, W1, b1v, W2, b2v, outSeq, outErr);
  }
}

// Round 6
// 121.483 us; speedup vs baseline: 3.5790x; 1.0903x over previous
//
#include <hip/hip_runtime.h>
#include <stdint.h>

#define LATENT 10
#define MAXLEN 80
#define STEPS  10
#define HIDDEN 32
#define BATCH  512
#define NSEG   8
#define SEGL   10   // MAXLEN / NSEG

// ---------------------------------------------------------------------------
// Threefry-2x32, 20 rounds — bit-exact replica of jax threefry2x32_p.
// ---------------------------------------------------------------------------
__device__ __forceinline__ void tf2x32(uint32_t k0, uint32_t k1,
                                       uint32_t x0, uint32_t x1,
                                       uint32_t& o0, uint32_t& o1) {
  uint32_t ks2 = k0 ^ k1 ^ 0x1BD11BDAu;
  uint32_t v0 = x0 + k0;
  uint32_t v1 = x1 + k1;
#define TF_R(rot) { v0 += v1; v1 = (v1 << (rot)) | (v1 >> (32 - (rot))); v1 ^= v0; }
  TF_R(13) TF_R(15) TF_R(26) TF_R(6)
  v0 += k1;  v1 += ks2 + 1u;
  TF_R(17) TF_R(29) TF_R(16) TF_R(24)
  v0 += ks2; v1 += k0 + 2u;
  TF_R(13) TF_R(15) TF_R(26) TF_R(6)
  v0 += k0;  v1 += k1 + 3u;
  TF_R(17) TF_R(29) TF_R(16) TF_R(24)
  v0 += k1;  v1 += ks2 + 4u;
  TF_R(13) TF_R(15) TF_R(26) TF_R(6)
  v0 += ks2; v1 += k0 + 5u;
#undef TF_R
  o0 = v0; o1 = v1;
}

// JAX uniform(-0.99999994, 1) bits -> sqrt(2)*erfinv(u)  (XLA Giles polynomial)
__device__ __forceinline__ float bits_to_normal(uint32_t bits) {
  const float lo = -0.99999994f;                                 // nextafter(-1, 0)
  float f = __uint_as_float((bits >> 9) | 0x3f800000u) - 1.0f;   // [0,1)
  float u = fmaf(f, 2.0f, lo);                                   // (hi-lo) rounds to 2.0f
  u = fmaxf(u, lo);
  float w = -log1pf(-u * u);
  float p;
  if (w < 5.0f) {
    w -= 2.5f;
    p = 2.81022636e-08f;
    p = fmaf(p, w, 3.43273939e-07f);
    p = fmaf(p, w, -3.5233877e-06f);
    p = fmaf(p, w, -4.39150654e-06f);
    p = fmaf(p, w, 0.00021858087f);
    p = fmaf(p, w, -0.00125372503f);
    p = fmaf(p, w, -0.00417768164f);
    p = fmaf(p, w, 0.246640727f);
    p = fmaf(p, w, 1.50140941f);
  } else {
    w = sqrtf(w) - 3.0f;
    p = -0.000200214257f;
    p = fmaf(p, w, 0.000100950558f);
    p = fmaf(p, w, 0.00134934322f);
    p = fmaf(p, w, -0.00367342844f);
    p = fmaf(p, w, 0.00573950773f);
    p = fmaf(p, w, -0.0076224613f);
    p = fmaf(p, w, 0.00943887047f);
    p = fmaf(p, w, 1.00167406f);
    p = fmaf(p, w, 2.83297682f);
  }
  return 1.4142135623730951f * (p * u);
}

// ---------------------------------------------------------------------------
// Fused phase 1.
// blocks [0,512): segmented prefix scans (8 segments of 10 l's).
//   localp[l][b][j] = sum over l' in seg(l), l'<l ;  segtot[s][b][j] = full seg sum
// blocks [512, 512+17600): normals, nrm[ik][b*10+d] (coalesced: element e=b*10+d).
//   subkey (block-uniform) computed once on lane 0, LDS-broadcast.
// ---------------------------------------------------------------------------
__global__ __launch_bounds__(256) void k_pre(
    const float* __restrict__ zmean, const float* __restrict__ W1,
    float* __restrict__ localp, float* __restrict__ segtot,
    float* __restrict__ nrm) {
  __shared__ uint32_t skk[2];
  if (blockIdx.x < 512) {
    int id = blockIdx.x * 256 + threadIdx.x;   // 0..131071
    int s = id >> 14;                          // segment, block-uniform
    int r = id & 16383;
    int b = r >> 5, j = r & 31;
    localp[((s * SEGL) * BATCH + b) * HIDDEN + j] = 0.0f;
    float pf0 = 0.0f, pf1 = 0.0f;
    for (int t = 1; t <= SEGL; ++t) {
      int l = s * SEGL + t - 1;
      const float2* mrow = (const float2*)(zmean + (b * MAXLEN + l) * LATENT);
      float2 m0 = mrow[0], m1 = mrow[1], m2 = mrow[2], m3 = mrow[3], m4 = mrow[4];
      const float* wl = W1 + (l * LATENT) * HIDDEN + j;
      pf0 = fmaf(m0.x, wl[0 * HIDDEN], pf0);
      pf1 = fmaf(m0.y, wl[1 * HIDDEN], pf1);
      pf0 = fmaf(m1.x, wl[2 * HIDDEN], pf0);
      pf1 = fmaf(m1.y, wl[3 * HIDDEN], pf1);
      pf0 = fmaf(m2.x, wl[4 * HIDDEN], pf0);
      pf1 = fmaf(m2.y, wl[5 * HIDDEN], pf1);
      pf0 = fmaf(m3.x, wl[6 * HIDDEN], pf0);
      pf1 = fmaf(m3.y, wl[7 * HIDDEN], pf1);
      pf0 = fmaf(m4.x, wl[8 * HIDDEN], pf0);
      pf1 = fmaf(m4.y, wl[9 * HIDDEN], pf1);
      if (t < SEGL)
        localp[((s * SEGL + t) * BATCH + b) * HIDDEN + j] = pf0 + pf1;
    }
    segtot[(s * BATCH + b) * HIDDEN + j] = pf0 + pf1;
  } else {
    int blk = blockIdx.x - 512;                // 0..17599
    int ik  = blk / 20;                        // block-uniform
    int e   = (blk % 20) * 256 + threadIdx.x;  // 0..5119, = b*10+d = counter x1
    if (threadIdx.x == 0) {
      uint32_t a, c;
      tf2x32(0u, 1337u, 0u, (uint32_t)ik, a, c);
      skk[0] = a; skk[1] = c;
    }
    __syncthreads();
    uint32_t o0, o1;
    tf2x32(skk[0], skk[1], 0u, (uint32_t)e, o0, o1);
    nrm[ik * 5120 + e] = bits_to_normal(o0 ^ o1);
  }
}

// ---------------------------------------------------------------------------
// Phase 2: 8 lanes per (i,b) chain; lane r owns hidden units [4r, 4r+4).
// 32 chains per 256-thread block; i block-uniform (16 blocks per i).
// Chain state kept normalized: u = (xt - mu)/sstd  (so logdx = -u, u0 = n0).
// ---------------------------------------------------------------------------
__global__ __launch_bounds__(256) void k_chain(
    const float* __restrict__ zmean, const float* __restrict__ zlv,
    const float* __restrict__ W1, const float* __restrict__ b1v,
    const float* __restrict__ W2, const float* __restrict__ b2v,
    const float* __restrict__ localp, const float* __restrict__ segtot,
    const float* __restrict__ nrm,
    float* __restrict__ outSeq, float* __restrict__ outErr) {
  const int tid = threadIdx.x;
  const int r = tid & 7;                       // lane-in-chain
  const int jb = r * 4;                        // first hidden unit of this lane
  const int i = blockIdx.x >> 4;               // block-uniform
  const int b = ((blockIdx.x & 15) << 5) + (tid >> 3);

  // ---- hidden-base: pf = localp[i] + sum of full segments + b1 + i*wT ----
  const float* rowT = W1 + (MAXLEN * LATENT) * HIDDEN;
  float pf[4], wT[4];
  {
    float4 l0 = *(const float4*)(localp + ((size_t)i * BATCH + b) * HIDDEN + jb);
    pf[0] = l0.x; pf[1] = l0.y; pf[2] = l0.z; pf[3] = l0.w;
    const int shi = i / SEGL;                  // uniform
    for (int s2 = 0; s2 < shi; ++s2) {
      float4 t0 = *(const float4*)(segtot + ((size_t)s2 * BATCH + b) * HIDDEN + jb);
      pf[0] += t0.x; pf[1] += t0.y; pf[2] += t0.z; pf[3] += t0.w;
    }
    const float fi = (float)i;
#pragma unroll
    for (int k = 0; k < 4; ++k) {
      wT[k] = rowT[jb + k];
      pf[k] = fmaf(fi, wT[k], pf[k] + b1v[jb + k]);
    }
  }

  // ---- replicated per-chain latent state (normalized) ----
  const int base = (b * MAXLEN + i) * LATENT;
  float mu[LATENT], sstd[LATENT], u[LATENT], errs[LATENT], b2[LATENT];
  {
    const float2* zm = (const float2*)(zmean + base);
    const float2* zl = (const float2*)(zlv + base);
#pragma unroll
    for (int p = 0; p < 5; ++p) {
      float2 m = zm[p], v = zl[p];
      mu[2 * p] = m.x; mu[2 * p + 1] = m.y;
      sstd[2 * p] = sqrtf(expf(v.x));
      sstd[2 * p + 1] = sqrtf(expf(v.y));
    }
  }
#pragma unroll
  for (int d = 0; d < LATENT; ++d) { b2[d] = b2v[d]; errs[d] = 0.0f; }

  const float* nbase = nrm + (size_t)(i * (STEPS + 1)) * (BATCH * LATENT) + b * LATENT;
  {
    const float2* np = (const float2*)nbase;   // k = 0 draw: u0 = n0 exactly
#pragma unroll
    for (int p = 0; p < 5; ++p) { float2 n = np[p]; u[2 * p] = n.x; u[2 * p + 1] = n.y; }
  }

  const float* W1i = W1 + (i * LATENT) * HIDDEN + jb;
  const float* W2q = W2 + jb * LATENT;
  const float SQRT_DT = 0.31622776601683794f;

  for (int s = 0; s < STEPS; ++s) {
    // this step's noise (k = s+1): 5 contiguous float2 (40 B, L1-broadcast)
    float nd[LATENT];
    {
      const float2* np = (const float2*)(nbase + (s + 1) * (BATCH * LATENT));
#pragma unroll
      for (int p = 0; p < 5; ++p) { float2 n = np[p]; nd[2 * p] = n.x; nd[2 * p + 1] = n.y; }
    }
    // xt = mu + sstd*u (for the MLP input)
    float xt[LATENT];
#pragma unroll
    for (int d = 0; d < LATENT; ++d) xt[d] = fmaf(sstd[d], u[d], mu[d]);

    const float ts = (float)s * 0.1f;
    float h[4];
#pragma unroll
    for (int k = 0; k < 4; ++k) h[k] = fmaf(ts, wT[k], pf[k]);
#pragma unroll
    for (int d = 0; d < LATENT; ++d) {
      const float xd = xt[d];
      float4 w = *(const float4*)(W1i + d * HIDDEN);
      h[0] = fmaf(xd, w.x, h[0]); h[1] = fmaf(xd, w.y, h[1]);
      h[2] = fmaf(xd, w.z, h[2]); h[3] = fmaf(xd, w.w, h[3]);
    }
    // partial score over this lane's 4 hidden units
    float sc[LATENT];
#pragma unroll
    for (int d = 0; d < LATENT; ++d) sc[d] = 0.0f;
#pragma unroll
    for (int k = 0; k < 4; ++k) {
      const float hj = fmaxf(h[k], 0.0f);
      const float2* w2r = (const float2*)(W2q + k * LATENT);
#pragma unroll
      for (int p = 0; p < 5; ++p) {
        float2 w = w2r[p];
        sc[2 * p] = fmaf(hj, w.x, sc[2 * p]);
        sc[2 * p + 1] = fmaf(hj, w.y, sc[2 * p + 1]);
      }
    }
    // reduce across the 8 lanes of the chain (xor 1,2 = DPP quad-perm; 4 = swizzle)
#pragma unroll
    for (int m = 1; m < 8; m <<= 1) {
#pragma unroll
      for (int d = 0; d < LATENT; ++d) sc[d] += __shfl_xor(sc[d], m);
    }
    // update (replicated): u += 0.5*sstd*st + sqrt(dt)*nd ; err += |u + st|
#pragma unroll
    for (int d = 0; d < LATENT; ++d) {
      float st = sc[d] + b2[d];
      errs[d] += fabsf(u[d] + st);             // |logdx - st| with logdx = -u
      float ndw = nd[d] * SQRT_DT;
      u[d] = u[d] + fmaf(0.5f * sstd[d], st, ndw);
    }
  }

  // ---- epilogue: lane (d & 7) stores dim d (lane0: d0,d8; lane1: d1,d9) ----
#pragma unroll
  for (int d = 0; d < LATENT; ++d) {
    if ((d & 7) == r) {
      outSeq[base + d] = fmaf(sstd[d], u[d], mu[d]);
      outErr[base + d] = errs[d];
    }
  }
}

// ---------------------------------------------------------------------------
// Fallback (ws too small): known-correct mono kernel.
// ---------------------------------------------------------------------------
__global__ __launch_bounds__(64) void k_mono(
    const float* __restrict__ zmean, const float* __restrict__ zlv,
    const float* __restrict__ W1, const float* __restrict__ b1v,
    const float* __restrict__ W2, const float* __restrict__ b2v,
    float* __restrict__ outSeq, float* __restrict__ outErr) {
  int i = blockIdx.x >> 3;
  int b = ((blockIdx.x & 7) << 6) + threadIdx.x;
  float pref[HIDDEN];
#pragma unroll
  for (int j = 0; j < HIDDEN; ++j) pref[j] = 0.0f;
  for (int l = 0; l < i; ++l) {
    const float* mrow = zmean + (b * MAXLEN + l) * LATENT;
    const float* wrow = W1 + (l * LATENT) * HIDDEN;
#pragma unroll
    for (int d = 0; d < LATENT; ++d) {
      float m = mrow[d];
#pragma unroll
      for (int j = 0; j < HIDDEN; ++j) pref[j] = fmaf(m, wrow[d * HIDDEN + j], pref[j]);
    }
  }
  const int base = (b * MAXLEN + i) * LATENT;
  float mu[LATENT], sstd[LATENT], xt[LATENT], errs[LATENT];
#pragma unroll
  for (int d = 0; d < LATENT; ++d) {
    mu[d] = zmean[base + d];
    sstd[d] = sqrtf(expf(zlv[base + d]));
  }
  float n0[LATENT];
  {
    uint32_t a, c;
    tf2x32(0u, 1337u, 0u, (uint32_t)(i * (STEPS + 1)), a, c);
#pragma unroll
    for (int d = 0; d < LATENT; ++d) {
      uint32_t o0, o1;
      tf2x32(a, c, 0u, (uint32_t)(b * LATENT + d), o0, o1);
      n0[d] = bits_to_normal(o0 ^ o1);
    }
  }
#pragma unroll
  for (int d = 0; d < LATENT; ++d) { xt[d] = mu[d] + sstd[d] * n0[d]; errs[d] = 0.0f; }
  const float* rowT  = W1 + (MAXLEN * LATENT) * HIDDEN;
  const float* rowsI = W1 + (i * LATENT) * HIDDEN;
  const float SQRT_DT = 0.31622776601683794f;
  for (int s = 0; s < STEPS; ++s) {
    float t = (float)i + (float)s * 0.1f;
    float h[HIDDEN];
#pragma unroll
    for (int j = 0; j < HIDDEN; ++j) h[j] = pref[j];
#pragma unroll
    for (int d = 0; d < LATENT; ++d) {
      float xd = xt[d];
      const float* row = rowsI + d * HIDDEN;
#pragma unroll
      for (int j = 0; j < HIDDEN; ++j) h[j] = fmaf(xd, row[j], h[j]);
    }
    float sc[LATENT];
#pragma unroll
    for (int d = 0; d < LATENT; ++d) sc[d] = b2v[d];
#pragma unroll
    for (int j = 0; j < HIDDEN; ++j) {
      float hj = fmaf(t, rowT[j], h[j]) + b1v[j];
      hj = fmaxf(hj, 0.0f);
      const float* w2r = W2 + j * LATENT;
#pragma unroll
      for (int d = 0; d < LATENT; ++d) sc[d] = fmaf(hj, w2r[d], sc[d]);
    }
    float nd[LATENT];
    {
      uint32_t a, c;
      tf2x32(0u, 1337u, 0u, (uint32_t)(i * (STEPS + 1) + s + 1), a, c);
#pragma unroll
      for (int d = 0; d < LATENT; ++d) {
        uint32_t o0, o1;
        tf2x32(a, c, 0u, (uint32_t)(b * LATENT + d), o0, o1);
        nd[d] = bits_to_normal(o0 ^ o1);
      }
    }
#pragma unroll
    for (int d = 0; d < LATENT; ++d) {
      float logdx = -(xt[d] - mu[d]) / sstd[d];
      errs[d] += fabsf(logdx - sc[d]);
      float dW = nd[d] * SQRT_DT;
      xt[d] = xt[d] + (0.5f * (sstd[d] * sstd[d])) * sc[d] + sstd[d] * dW;
    }
  }
#pragma unroll
  for (int d = 0; d < LATENT; ++d) {
    outSeq[base + d] = xt[d];
    outErr[base + d] = errs[d];
  }
}

// ---------------------------------------------------------------------------
extern "C" void kernel_launch(void* const* d_in, const int* in_sizes, int n_in,
                              void* d_out, int out_size, void* d_ws, size_t ws_size,
                              hipStream_t stream) {
  (void)in_sizes; (void)n_in; (void)out_size;
  const float* zmean = (const float*)d_in[0];
  const float* zlv   = (const float*)d_in[1];
  const float* W1    = (const float*)d_in[2];
  const float* b1v   = (const float*)d_in[3];
  const float* W2    = (const float*)d_in[4];
  const float* b2v   = (const float*)d_in[5];
  float* outSeq = (float*)d_out;
  float* outErr = outSeq + (size_t)BATCH * MAXLEN * LATENT;

  const size_t nrmBytes   = (size_t)MAXLEN * (STEPS + 1) * BATCH * LATENT * sizeof(float); // 18,022,400
  const size_t localBytes = (size_t)MAXLEN * BATCH * HIDDEN * sizeof(float);               // 5,242,880
  const size_t segBytes   = (size_t)NSEG * BATCH * HIDDEN * sizeof(float);                 // 524,288

  if (ws_size >= nrmBytes + localBytes + segBytes) {
    float* nrm    = (float*)d_ws;
    float* localp = (float*)((char*)d_ws + nrmBytes);
    float* segtot = (float*)((char*)d_ws + nrmBytes + localBytes);
    hipLaunchKernelGGL(k_pre, dim3(512 + MAXLEN * (STEPS + 1) * 20), dim3(256), 0, stream,
                       zmean, W1, localp, segtot, nrm);
    hipLaunchKernelGGL(k_chain, dim3(MAXLEN * 16), dim3(256), 0, stream,
                       zmean, zlv, W1, b1v, W2, b2v, localp, segtot, nrm, outSeq, outErr);
  } else {
    hipLaunchKernelGGL(k_mono, dim3(MAXLEN * 8), dim3(64), 0, stream,
                       zmean, zlv, W1, b1v, W2, b2v, outSeq, outErr);
  }
}